// Round 5
// baseline (410.675 us; speedup 1.0000x reference)
//
#include <hip/hip_runtime.h>
#include <hip/hip_fp16.h>
#include <math.h>
#include <stdint.h>

// ---------------- problem constants ----------------
#define CUTOFF_F     5.0f
#define INV_CUTOFF   0.2f
#define KCOUL        14.3996454784936f
#define INV_SQRT2    0.7071067811865475f

// clang native vectors (HIP_vector_type is rejected by nontemporal builtins)
typedef int            vint4    __attribute__((ext_vector_type(4)));
typedef float          vfloat4  __attribute__((ext_vector_type(4)));
typedef uint32_t       vuint4   __attribute__((ext_vector_type(4)));
typedef unsigned short vushort4 __attribute__((ext_vector_type(4)));

// ---------------- plan ----------------
// ROUND-5: GLOBAL BUCKET-CONTIGUOUS SORT.
// Rounds 0-4 showed p2 pinned at ~155us across every walk structure and
// occupancy level: concurrency = waves x in-flight-loads/wave never rose
// (r3: 52 VGPR but 41% occ; r4: 74% occ but 16 VGPR), and the serial
// cum[]-walk (~120cy/dependent LDS trip) sat in every edge's path.
// Fix: p1 blocks atomically reserve per-bucket global space
// (base = atomicAdd(ctr[b], len); within-bucket order irrelevant - sum is
// commutative) and scatter their LDS-sorted runs to b*CAP + base. Buckets
// become DENSE SLABS: p2 does aligned uint4 loads of 4 records/lane ->
// 4 independent sigma gathers -> 4 edge_vals -> 4 LDS atomics. No offset
// table, no walk, 4-deep MLP by construction, VGPRs preserved via (256,6).
#define WSHIFT        11
#define WINDOW        2048
#define NB            245                      // ceil(500000/2048)
#define WGS_PER_B     8
#define NWG2          (NB * WGS_PER_B)         // 1960
#define EPT           8
#define EPB           4096                     // 2 batches * 256 thr * 8
#define CAP           71680                    // mean 65536 + 24 sigma, /256=280

// A&S 7.1.26 erf approx, x>=0, max abs err 1.5e-7
__device__ __forceinline__ float erf_approx(float x) {
    const float a1 = 0.254829592f, a2 = -0.284496736f, a3 = 1.421413741f,
                a4 = -1.453152027f, a5 = 1.061405429f, p = 0.3275911f;
    float t = __builtin_amdgcn_rcpf(fmaf(p, x, 1.0f));
    float poly = t * fmaf(t, fmaf(t, fmaf(t, fmaf(t, a5, a4), a3), a2), a1);
    return 1.0f - poly * __expf(-x * x);
}

// per-edge value WITHOUT the charge[dst] factor; s2sum = sig_s^2 + sig_d^2
__device__ __forceinline__ float edge_val(float rr, float s2sum) {
    float inv_gamma = rsqrtf(s2sum);
    float x  = rr * INV_CUTOFF;
    float fc = fmaf(x * x * x, fmaf(x, fmaf(-6.0f, x, 15.0f), -10.0f), 1.0f);
    fc = (rr <= CUTOFF_F) ? fc : 0.0f;
    return erf_approx(rr * INV_SQRT2 * inv_gamma) * fc * KCOUL
         * __builtin_amdgcn_rcpf(rr);
}

// ---------------- pass 1: counting-sort + global bucket-slab scatter ----------------
__global__ __launch_bounds__(256, 4) void p1_bin(
    const float* __restrict__ bond,
    const int*   __restrict__ src,
    const int*   __restrict__ dst,
    uint32_t*       __restrict__ ctr,     // [NB] global per-bucket counters
    uint32_t*       __restrict__ sl_out,  // [NB][CAP] (src<<11 | local_dst)
    unsigned short* __restrict__ r_out,   // [NB][CAP] fp16 bond length
    int n_edges)
{
    __shared__ uint32_t hist[NB];
    __shared__ uint32_t scan_s[NB + 1];
    __shared__ uint32_t gbase[NB];
    __shared__ alignas(16) uint32_t       buf_sl[EPB];   // 16 KB
    __shared__ alignas(16) unsigned short buf_r[EPB];    //  8 KB
    __shared__ uint8_t  bkt[EPB];                        //  4 KB

    const int tid = threadIdx.x;
    const int e0  = blockIdx.x * EPB;

    if (tid < NB) hist[tid] = 0;
    __syncthreads();

    int   dA[EPT], sA[EPT], dB[EPT], sB[EPT];
    float rA[EPT], rB[EPT];
    const bool full = (e0 + EPB <= n_edges);
    if (full) {
        const vint4*   dp = (const vint4*)(dst + e0) + tid;
        const vint4*   sp = (const vint4*)(src + e0) + tid;
        const vfloat4* rp = (const vfloat4*)(bond + e0) + tid;
        vint4 d0 = __builtin_nontemporal_load(dp);
        vint4 d1 = __builtin_nontemporal_load(dp + 256);
        vint4 s0 = __builtin_nontemporal_load(sp);
        vint4 s1 = __builtin_nontemporal_load(sp + 256);
        vfloat4 r0 = __builtin_nontemporal_load(rp);
        vfloat4 r1 = __builtin_nontemporal_load(rp + 256);
        vint4 d2 = __builtin_nontemporal_load(dp + 512);
        vint4 d3 = __builtin_nontemporal_load(dp + 768);
        vint4 s2 = __builtin_nontemporal_load(sp + 512);
        vint4 s3 = __builtin_nontemporal_load(sp + 768);
        vfloat4 r2 = __builtin_nontemporal_load(rp + 512);
        vfloat4 r3 = __builtin_nontemporal_load(rp + 768);
        dA[0]=d0.x; dA[1]=d0.y; dA[2]=d0.z; dA[3]=d0.w;
        dA[4]=d1.x; dA[5]=d1.y; dA[6]=d1.z; dA[7]=d1.w;
        sA[0]=s0.x; sA[1]=s0.y; sA[2]=s0.z; sA[3]=s0.w;
        sA[4]=s1.x; sA[5]=s1.y; sA[6]=s1.z; sA[7]=s1.w;
        rA[0]=r0.x; rA[1]=r0.y; rA[2]=r0.z; rA[3]=r0.w;
        rA[4]=r1.x; rA[5]=r1.y; rA[6]=r1.z; rA[7]=r1.w;
        dB[0]=d2.x; dB[1]=d2.y; dB[2]=d2.z; dB[3]=d2.w;
        dB[4]=d3.x; dB[5]=d3.y; dB[6]=d3.z; dB[7]=d3.w;
        sB[0]=s2.x; sB[1]=s2.y; sB[2]=s2.z; sB[3]=s2.w;
        sB[4]=s3.x; sB[5]=s3.y; sB[6]=s3.z; sB[7]=s3.w;
        rB[0]=r2.x; rB[1]=r2.y; rB[2]=r2.z; rB[3]=r2.w;
        rB[4]=r3.x; rB[5]=r3.y; rB[6]=r3.z; rB[7]=r3.w;
    } else {
        #pragma unroll
        for (int j = 0; j < EPT; ++j) {
            int eA = e0 + (j >> 2) * 1024 + tid * 4 + (j & 3);
            int eB = eA + 2048;
            if (eA < n_edges) { dA[j] = dst[eA]; sA[j] = src[eA]; rA[j] = bond[eA]; }
            else dA[j] = -1;
            if (eB < n_edges) { dB[j] = dst[eB]; sB[j] = src[eB]; rB[j] = bond[eB]; }
            else dB[j] = -1;
        }
    }

    // pack + rank (rank = histogram atomicAdd return) — no global traffic
    uint32_t slA[EPT], brA[EPT], slB[EPT], brB[EPT];
    unsigned short hrA[EPT], hrB[EPT];
    #pragma unroll
    for (int j = 0; j < EPT; ++j) {
        if (dA[j] >= 0) {
            unsigned b = (unsigned)dA[j] >> WSHIFT;
            uint32_t r = atomicAdd(&hist[b], 1u);
            brA[j] = (b << 16) | r;
            slA[j] = ((uint32_t)sA[j] << WSHIFT) | ((unsigned)dA[j] & (WINDOW - 1));
            hrA[j] = __half_as_ushort(__float2half_rn(rA[j]));
        } else brA[j] = 0xFFFFFFFFu;
    }
    #pragma unroll
    for (int j = 0; j < EPT; ++j) {
        if (dB[j] >= 0) {
            unsigned b = (unsigned)dB[j] >> WSHIFT;
            uint32_t r = atomicAdd(&hist[b], 1u);
            brB[j] = (b << 16) | r;
            slB[j] = ((uint32_t)sB[j] << WSHIFT) | ((unsigned)dB[j] & (WINDOW - 1));
            hrB[j] = __half_as_ushort(__float2half_rn(rB[j]));
        } else brB[j] = 0xFFFFFFFFu;
    }
    __syncthreads();

    // wave scan over NB buckets, 4 elems/lane (first wave)
    if (tid < 64) {
        const int base = tid * 4;
        uint32_t v[4]; uint32_t s = 0;
        #pragma unroll
        for (int j = 0; j < 4; ++j) { v[j] = (base + j < NB) ? hist[base + j] : 0u; s += v[j]; }
        uint32_t inc = s;
        #pragma unroll
        for (int d = 1; d < 64; d <<= 1) {
            uint32_t up = __shfl_up(inc, d, 64);
            if (tid >= d) inc += up;
        }
        uint32_t excl = inc - s;
        #pragma unroll
        for (int j = 0; j < 4; ++j) {
            if (base + j <= NB) scan_s[base + j] = excl;
            excl += v[j];
        }
    }
    __syncthreads();

    // register -> LDS scatter at scan[b] + rank (also record bucket id)
    #pragma unroll
    for (int j = 0; j < EPT; ++j)
        if (brA[j] != 0xFFFFFFFFu) {
            uint32_t p = scan_s[brA[j] >> 16] + (brA[j] & 0xFFFFu);
            buf_sl[p] = slA[j]; buf_r[p] = hrA[j]; bkt[p] = (uint8_t)(brA[j] >> 16);
        }
    #pragma unroll
    for (int j = 0; j < EPT; ++j)
        if (brB[j] != 0xFFFFFFFFu) {
            uint32_t p = scan_s[brB[j] >> 16] + (brB[j] & 0xFFFFu);
            buf_sl[p] = slB[j]; buf_r[p] = hrB[j]; bkt[p] = (uint8_t)(brB[j] >> 16);
        }

    // reserve global space per bucket (order within bucket is irrelevant)
    if (tid < NB) {
        uint32_t len = scan_s[tid + 1] - scan_s[tid];
        uint32_t base = atomicAdd(&ctr[tid], len);
        gbase[tid] = (uint32_t)tid * CAP + base - scan_s[tid];
    }
    __syncthreads();

    // scatter runs to global bucket slabs (consecutive p -> consecutive addr
    // within a run; run avg ~17 records => mostly-contiguous segments)
    const int total = (int)scan_s[NB];
    #pragma unroll
    for (int i = 0; i < EPB / 256; ++i) {
        int p = tid + i * 256;
        if (p < total) {
            unsigned bb = bkt[p];
            uint32_t addr = gbase[bb] + (uint32_t)p;
            __builtin_nontemporal_store(buf_sl[p], sl_out + addr);
            __builtin_nontemporal_store(buf_r[p],  r_out + addr);
        }
    }
}

// ---------------- pass 2: dense-slab physics + LDS-window accumulate ----------------
// Each WG owns 1/8 of bucket b's contiguous slab. Per lane-iteration:
// aligned uint4 load (4 sl records) + 8B load (4 fp16 r) -> 4 independent
// sigma[src] gathers -> 4 edge_vals -> 4 LDS atomics. 4-deep MLP/lane.
__global__ __launch_bounds__(256, 6) void p2_acc(
    const uint32_t*       __restrict__ sl_in,
    const unsigned short* __restrict__ r_in,
    const uint32_t*       __restrict__ ctr,
    const float*          __restrict__ sigma,
    float*                __restrict__ partials,  // [NWG2][WINDOW]
    int n_nodes)
{
    __shared__ float acc[WINDOW];                  // 8 KB
    __shared__ float sig[WINDOW];                  // 8 KB — dst-side sigma

    const int g = blockIdx.x;
    const int b = g / WGS_PER_B;
    const int w = g % WGS_PER_B;

    vfloat4* accv = (vfloat4*)acc;
    for (int i = threadIdx.x; i < WINDOW / 4; i += 256)
        accv[i] = (vfloat4){0.f, 0.f, 0.f, 0.f};

    const int nbase  = b << WSHIFT;
    const int nvalid = (n_nodes - nbase < WINDOW) ? (n_nodes - nbase) : WINDOW;
    if (nvalid == WINDOW) {
        vfloat4* sv = (vfloat4*)sig;
        const vfloat4* gp = (const vfloat4*)(sigma + nbase);
        for (int i = threadIdx.x; i < WINDOW / 4; i += 256) sv[i] = gp[i];
    } else {
        for (int i = threadIdx.x; i < WINDOW; i += 256)
            sig[i] = (i < nvalid) ? sigma[nbase + i] : 0.f;
    }
    __syncthreads();

    const uint32_t cnt   = ctr[b];
    uint32_t chunk = (((cnt + WGS_PER_B - 1) / WGS_PER_B) + 3u) & ~3u;
    const uint32_t start = (uint32_t)w * chunk;
    uint32_t end = start + chunk;
    if (end > cnt) end = cnt;

    const uint32_t*       slb = sl_in + (size_t)b * CAP;
    const unsigned short* rb  = r_in  + (size_t)b * CAP;

    for (uint32_t r0 = start + (uint32_t)threadIdx.x * 4u; r0 < end; r0 += 1024u) {
        vuint4   sl4 = *(const vuint4*)(slb + r0);       // 16B aligned
        vushort4 r4  = *(const vushort4*)(rb + r0);      //  8B aligned
        #pragma unroll
        for (int j = 0; j < 4; ++j) {
            if (r0 + (uint32_t)j < end) {
                uint32_t sl = sl4[j];
                float rr = __half2float(__ushort_as_half(r4[j]));
                float ss = sigma[sl >> WSHIFT];
                float sd = sig[sl & (WINDOW - 1)];
                float v  = edge_val(rr, fmaf(ss, ss, sd * sd));
                atomicAdd(&acc[sl & (WINDOW - 1)], v);
            }
        }
    }
    __syncthreads();

    // coalesced nt float4 flush
    vfloat4* outp = (vfloat4*)(partials + (size_t)g * WINDOW);
    for (int i = threadIdx.x; i < WINDOW / 4; i += 256)
        __builtin_nontemporal_store(accv[i], outp + i);
}

// ---------------- pass 3: reduce partials, apply charge ----------------
__global__ __launch_bounds__(256) void p3_reduce(
    const float* __restrict__ partials,
    const float* __restrict__ charge,
    float*       __restrict__ out, int n_nodes)
{
    int n = blockIdx.x * 256 + threadIdx.x;
    if (n >= n_nodes) return;
    unsigned b     = (unsigned)n >> WSHIFT;
    unsigned local = (unsigned)n & (WINDOW - 1);
    const float* p = partials + ((size_t)b * WGS_PER_B) * WINDOW + local;
    float sum = 0.0f;
    #pragma unroll
    for (int w = 0; w < WGS_PER_B; ++w)
        sum += __builtin_nontemporal_load(p + (size_t)w * WINDOW);
    out[n] = charge[n] * sum;
}

// ---------------- fallback: direct far-atomic ----------------
__global__ __launch_bounds__(256) void edge_msg_atomic(
    const float* __restrict__ charge, const float* __restrict__ sigma,
    const float* __restrict__ bond, const int* __restrict__ src,
    const int* __restrict__ dst, float* __restrict__ out, int n_edges)
{
    int i = blockIdx.x * blockDim.x + threadIdx.x;
    if (i < n_edges) {
        float ss = sigma[src[i]], sd = sigma[dst[i]];
        float msg = charge[dst[i]] * edge_val(bond[i], fmaf(ss, ss, sd * sd));
        atomicAdd(&out[dst[i]], msg);
    }
}

extern "C" void kernel_launch(void* const* d_in, const int* in_sizes, int n_in,
                              void* d_out, int out_size, void* d_ws, size_t ws_size,
                              hipStream_t stream) {
    const float* charge = (const float*)d_in[0];
    const float* sigma  = (const float*)d_in[1];
    const float* bond   = (const float*)d_in[2];
    const int*   src    = (const int*)d_in[3];
    const int*   dst    = (const int*)d_in[4];
    float* out = (float*)d_out;

    int n_nodes = in_sizes[0];
    int n_edges = in_sizes[2];

    int nblk = (n_edges + EPB - 1) / EPB;

    // ws: ctr [NB] u32 (1KB pad) | sl [NB][CAP] u32 | r [NB][CAP] u16 | partials
    size_t ctr_b  = 1024;
    size_t sl_b   = (size_t)NB * CAP * sizeof(uint32_t);
    size_t r_b    = (size_t)NB * CAP * sizeof(unsigned short);
    size_t part_b = (size_t)NWG2 * WINDOW * sizeof(float);
    size_t need   = ctr_b + sl_b + r_b + part_b;

    // CAP covers mean 65536 + 24 sigma for uniform-random dst; guard anyway:
    // worst legal per-bucket count is n_edges, so require n_edges' mean fit
    bool cap_ok = ((size_t)n_edges <= (size_t)NB * CAP);

    if (n_nodes <= NB * WINDOW && need <= ws_size && cap_ok &&
        n_edges >= (1 << 20)) {
        uint32_t*       ctrp = (uint32_t*)d_ws;
        uint32_t*       slp  = (uint32_t*)((char*)d_ws + ctr_b);
        unsigned short* rp   = (unsigned short*)((char*)d_ws + ctr_b + sl_b);
        float* partial = (float*)((char*)d_ws + ctr_b + sl_b + r_b);

        (void)hipMemsetAsync(ctrp, 0, NB * sizeof(uint32_t), stream);
        p1_bin<<<nblk, 256, 0, stream>>>(bond, src, dst, ctrp, slp, rp, n_edges);
        p2_acc<<<NWG2, 256, 0, stream>>>(slp, rp, ctrp, sigma, partial, n_nodes);
        int blocks3 = (n_nodes + 255) / 256;
        p3_reduce<<<blocks3, 256, 0, stream>>>(partial, charge, out, n_nodes);
    } else {
        // fallback: direct atomics (correct, slower)
        (void)hipMemsetAsync(out, 0, (size_t)n_nodes * sizeof(float), stream);
        int blocks = (n_edges + 255) / 256;
        edge_msg_atomic<<<blocks, 256, 0, stream>>>(charge, sigma, bond, src, dst,
                                                    out, n_edges);
    }
}

// Round 6
// 329.229 us; speedup vs baseline: 1.2474x; 1.2474x over previous
//
#include <hip/hip_runtime.h>
#include <hip/hip_fp16.h>
#include <math.h>
#include <stdint.h>

// ---------------- problem constants ----------------
#define CUTOFF_F     5.0f
#define INV_CUTOFF   0.2f
#define KCOUL        14.3996454784936f
#define INV_SQRT2    0.7071067811865475f

// clang native vectors (HIP_vector_type is rejected by nontemporal builtins)
typedef int            vint4    __attribute__((ext_vector_type(4)));
typedef float          vfloat4  __attribute__((ext_vector_type(4)));
typedef uint32_t       vuint4   __attribute__((ext_vector_type(4)));
typedef unsigned short vushort8 __attribute__((ext_vector_type(8)));

// ---------------- plan ----------------
// ROUND-6: the decisive occupancy x ILP experiment for p2.
// Evidence matrix: r3 = 41% occ x 52 VGPR -> 160us; r4 = 74% occ x 16 VGPR
// (launch_bounds(256,8) over-throttled the RA) -> 154us. The untested cell
// is high-occ x healthy-VGPR: 52 VGPR already permits 32 waves/CU (<64),
// r3's real limit was the GRID (984 WGs = 3.84 WG/CU). So: WGS_PER_B 16
// (grid 3920 = 15.3 WG/CU; LDS 19.5KB caps at 8 WG/CU = 32 waves = 100%)
// with launch_bounds(256,4) for r3's known-good 52-VGPR codegen.
// p1 REVERTED to block-major coalesced dump (r5's slab scatter: WRITE
// 98->174MB amplification, p1 172us, total 410 - abandoned).
// p2 loads plain (not nt): ride L3 warm with p1's dump (r4 nt loads
// doubled FETCH for nothing).
#define WSHIFT        11
#define WINDOW        2048
#define NB            245                       // ceil(500000/2048)
#define EPT           8
#define EPB           4096                      // 2 batches * 256 thr * 8
#define OFFS_STRIDE   256                       // u16 slots per block (246 used)
#define SPAN_MAX      512                       // max p1-blocks per p2 wg

// A&S 7.1.26 erf approx, x>=0, max abs err 1.5e-7
__device__ __forceinline__ float erf_approx(float x) {
    const float a1 = 0.254829592f, a2 = -0.284496736f, a3 = 1.421413741f,
                a4 = -1.453152027f, a5 = 1.061405429f, p = 0.3275911f;
    float t = __builtin_amdgcn_rcpf(fmaf(p, x, 1.0f));
    float poly = t * fmaf(t, fmaf(t, fmaf(t, fmaf(t, a5, a4), a3), a2), a1);
    return 1.0f - poly * __expf(-x * x);
}

// per-edge value WITHOUT the charge[dst] factor; s2sum = sig_s^2 + sig_d^2
__device__ __forceinline__ float edge_val(float rr, float s2sum) {
    float inv_gamma = rsqrtf(s2sum);
    float x  = rr * INV_CUTOFF;
    float fc = fmaf(x * x * x, fmaf(x, fmaf(-6.0f, x, 15.0f), -10.0f), 1.0f);
    fc = (rr <= CUTOFF_F) ? fc : 0.0f;
    return erf_approx(rr * INV_SQRT2 * inv_gamma) * fc * KCOUL
         * __builtin_amdgcn_rcpf(rr);
}

// ---------------- pass 1: block-major streaming counting-sort ----------------
__global__ __launch_bounds__(256, 6) void p1_bin(
    const float* __restrict__ bond,
    const int*   __restrict__ src,
    const int*   __restrict__ dst,
    unsigned short* __restrict__ offs,    // [nblk][OFFS_STRIDE] u16 scan table
    uint32_t*       __restrict__ sl_out,  // [nblk][EPB] (src<<11 | local_dst)
    unsigned short* __restrict__ r_out,   // [nblk][EPB] fp16 bond length
    int n_edges)
{
    __shared__ uint32_t hist[NB];
    __shared__ uint32_t scan_s[NB + 1];
    __shared__ alignas(16) uint32_t       buf_sl[EPB];   // 16 KB
    __shared__ alignas(16) unsigned short buf_r[EPB];    //  8 KB

    const int tid = threadIdx.x;
    const int e0  = blockIdx.x * EPB;

    if (tid < NB) hist[tid] = 0;
    __syncthreads();

    int   dA[EPT], sA[EPT], dB[EPT], sB[EPT];
    float rA[EPT], rB[EPT];
    const bool full = (e0 + EPB <= n_edges);
    if (full) {
        const vint4*   dp = (const vint4*)(dst + e0) + tid;
        const vint4*   sp = (const vint4*)(src + e0) + tid;
        const vfloat4* rp = (const vfloat4*)(bond + e0) + tid;
        vint4 d0 = __builtin_nontemporal_load(dp);
        vint4 d1 = __builtin_nontemporal_load(dp + 256);
        vint4 s0 = __builtin_nontemporal_load(sp);
        vint4 s1 = __builtin_nontemporal_load(sp + 256);
        vfloat4 r0 = __builtin_nontemporal_load(rp);
        vfloat4 r1 = __builtin_nontemporal_load(rp + 256);
        vint4 d2 = __builtin_nontemporal_load(dp + 512);
        vint4 d3 = __builtin_nontemporal_load(dp + 768);
        vint4 s2 = __builtin_nontemporal_load(sp + 512);
        vint4 s3 = __builtin_nontemporal_load(sp + 768);
        vfloat4 r2 = __builtin_nontemporal_load(rp + 512);
        vfloat4 r3 = __builtin_nontemporal_load(rp + 768);
        dA[0]=d0.x; dA[1]=d0.y; dA[2]=d0.z; dA[3]=d0.w;
        dA[4]=d1.x; dA[5]=d1.y; dA[6]=d1.z; dA[7]=d1.w;
        sA[0]=s0.x; sA[1]=s0.y; sA[2]=s0.z; sA[3]=s0.w;
        sA[4]=s1.x; sA[5]=s1.y; sA[6]=s1.z; sA[7]=s1.w;
        rA[0]=r0.x; rA[1]=r0.y; rA[2]=r0.z; rA[3]=r0.w;
        rA[4]=r1.x; rA[5]=r1.y; rA[6]=r1.z; rA[7]=r1.w;
        dB[0]=d2.x; dB[1]=d2.y; dB[2]=d2.z; dB[3]=d2.w;
        dB[4]=d3.x; dB[5]=d3.y; dB[6]=d3.z; dB[7]=d3.w;
        sB[0]=s2.x; sB[1]=s2.y; sB[2]=s2.z; sB[3]=s2.w;
        sB[4]=s3.x; sB[5]=s3.y; sB[6]=s3.z; sB[7]=s3.w;
        rB[0]=r2.x; rB[1]=r2.y; rB[2]=r2.z; rB[3]=r2.w;
        rB[4]=r3.x; rB[5]=r3.y; rB[6]=r3.z; rB[7]=r3.w;
    } else {
        #pragma unroll
        for (int j = 0; j < EPT; ++j) {
            int eA = e0 + (j >> 2) * 1024 + tid * 4 + (j & 3);
            int eB = eA + 2048;
            if (eA < n_edges) { dA[j] = dst[eA]; sA[j] = src[eA]; rA[j] = bond[eA]; }
            else dA[j] = -1;
            if (eB < n_edges) { dB[j] = dst[eB]; sB[j] = src[eB]; rB[j] = bond[eB]; }
            else dB[j] = -1;
        }
    }

    // pack + rank (rank = histogram atomicAdd return) — no global traffic
    uint32_t slA[EPT], brA[EPT], slB[EPT], brB[EPT];
    unsigned short hrA[EPT], hrB[EPT];
    #pragma unroll
    for (int j = 0; j < EPT; ++j) {
        if (dA[j] >= 0) {
            unsigned b = (unsigned)dA[j] >> WSHIFT;
            uint32_t r = atomicAdd(&hist[b], 1u);
            brA[j] = (b << 16) | r;
            slA[j] = ((uint32_t)sA[j] << WSHIFT) | ((unsigned)dA[j] & (WINDOW - 1));
            hrA[j] = __half_as_ushort(__float2half_rn(rA[j]));
        } else brA[j] = 0xFFFFFFFFu;
    }
    #pragma unroll
    for (int j = 0; j < EPT; ++j) {
        if (dB[j] >= 0) {
            unsigned b = (unsigned)dB[j] >> WSHIFT;
            uint32_t r = atomicAdd(&hist[b], 1u);
            brB[j] = (b << 16) | r;
            slB[j] = ((uint32_t)sB[j] << WSHIFT) | ((unsigned)dB[j] & (WINDOW - 1));
            hrB[j] = __half_as_ushort(__float2half_rn(rB[j]));
        } else brB[j] = 0xFFFFFFFFu;
    }
    __syncthreads();

    // wave scan over NB buckets, 4 elems/lane (first wave, 256 >= NB+1)
    if (tid < 64) {
        const int base = tid * 4;
        uint32_t v[4]; uint32_t s = 0;
        #pragma unroll
        for (int j = 0; j < 4; ++j) { v[j] = (base + j < NB) ? hist[base + j] : 0u; s += v[j]; }
        uint32_t inc = s;
        #pragma unroll
        for (int d = 1; d < 64; d <<= 1) {
            uint32_t up = __shfl_up(inc, d, 64);
            if (tid >= d) inc += up;
        }
        uint32_t excl = inc - s;
        #pragma unroll
        for (int j = 0; j < 4; ++j) {
            if (base + j <= NB) scan_s[base + j] = excl;
            excl += v[j];
        }
    }
    __syncthreads();

    // register -> LDS scatter at scan[b] + rank
    #pragma unroll
    for (int j = 0; j < EPT; ++j)
        if (brA[j] != 0xFFFFFFFFu) {
            uint32_t p = scan_s[brA[j] >> 16] + (brA[j] & 0xFFFFu);
            buf_sl[p] = slA[j]; buf_r[p] = hrA[j];
        }
    #pragma unroll
    for (int j = 0; j < EPT; ++j)
        if (brB[j] != 0xFFFFFFFFu) {
            uint32_t p = scan_s[brB[j] >> 16] + (brB[j] & 0xFFFFu);
            buf_sl[p] = slB[j]; buf_r[p] = hrB[j];
        }
    __syncthreads();

    // offset table: the LDS scan, dumped as u16 (246 entries)
    if (tid <= NB)
        offs[(size_t)blockIdx.x * OFFS_STRIDE + tid] = (unsigned short)scan_s[tid];

    // dense block-major dump: fully coalesced vector stores, no checks
    {
        const vuint4* bs = (const vuint4*)buf_sl;
        vuint4* os = (vuint4*)(sl_out + (size_t)blockIdx.x * EPB);
        #pragma unroll
        for (int i = 0; i < EPB / 4 / 256; ++i)      // 4 iterations
            __builtin_nontemporal_store(bs[tid + i * 256], os + tid + i * 256);
        const vushort8* br = (const vushort8*)buf_r;
        vushort8* orr = (vushort8*)(r_out + (size_t)blockIdx.x * EPB);
        #pragma unroll
        for (int i = 0; i < EPB / 8 / 256; ++i)      // 2 iterations
            __builtin_nontemporal_store(br[tid + i * 256], orr + tid + i * 256);
    }
}

// ---------------- pass 2: flat dense walk + LDS-window accumulate ----------------
// LDS ~19.5KB -> 8 WG/CU; grid NB*WPB (WPB=16: 3920 = 15.3 WG/CU) -> the
// LDS cap binds: 32 waves/CU. launch_bounds(256,4) keeps r3's 52-VGPR
// codegen (52 < 64 still allows 8 waves/EU per m69 thresholds).
template<int WPB>
__global__ __launch_bounds__(256, 4) void p2_acc(
    const uint32_t*       __restrict__ sl_in,
    const unsigned short* __restrict__ r_in,
    const unsigned short* __restrict__ offs,
    const float*          __restrict__ sigma,
    float*                __restrict__ partials,  // [NB*WPB][WINDOW]
    int n_nodes, int nblk)
{
    __shared__ float acc[WINDOW];                  // 8 KB
    __shared__ float sig[WINDOW];                  // 8 KB — dst-side sigma
    __shared__ unsigned short offLo[SPAN_MAX];     // 1 KB
    __shared__ uint32_t cum[SPAN_MAX + 1];         // 2 KB — flat prefix of run lens

    const int g = blockIdx.x;
    const int b = g / WPB;
    const int w = g % WPB;

    vfloat4* accv = (vfloat4*)acc;
    for (int i = threadIdx.x; i < WINDOW / 4; i += 256)
        accv[i] = (vfloat4){0.f, 0.f, 0.f, 0.f};

    const int nbase  = b << WSHIFT;
    const int nvalid = (n_nodes - nbase < WINDOW) ? (n_nodes - nbase) : WINDOW;
    if (nvalid == WINDOW) {
        vfloat4* sv = (vfloat4*)sig;
        const vfloat4* gp = (const vfloat4*)(sigma + nbase);
        for (int i = threadIdx.x; i < WINDOW / 4; i += 256) sv[i] = gp[i];
    } else {
        for (int i = threadIdx.x; i < WINDOW; i += 256)
            sig[i] = (i < nvalid) ? sigma[nbase + i] : 0.f;
    }

    // my span of p1 blocks; stage offLo + run lengths (len into cum[] temp)
    const int span = (nblk + WPB - 1) / WPB;
    const int blk0 = w * span;
    int blkN = nblk - blk0;
    if (blkN > span) blkN = span;
    if (blkN < 0) blkN = 0;
    for (int i = threadIdx.x; i < blkN; i += 256) {
        size_t o = (size_t)(blk0 + i) * OFFS_STRIDE + b;
        unsigned short lo = offs[o];
        offLo[i] = lo;
        cum[i] = (uint32_t)offs[o + 1] - lo;     // run length (temp)
    }
    __syncthreads();

    // wave-0 exclusive scan of run lengths, 8 elems/lane (SPAN_MAX=512=64*8).
    // Positions >= blkN scan zeros, so cum[blkN] = total automatically.
    if (threadIdx.x < 64) {
        const int base = threadIdx.x * 8;
        uint32_t v[8]; uint32_t s = 0;
        #pragma unroll
        for (int j = 0; j < 8; ++j) { v[j] = (base + j < blkN) ? cum[base + j] : 0u; s += v[j]; }
        uint32_t inc = s;
        #pragma unroll
        for (int d = 1; d < 64; d <<= 1) {
            uint32_t up = __shfl_up(inc, d, 64);
            if (threadIdx.x >= d) inc += up;
        }
        uint32_t excl = inc - s;
        #pragma unroll
        for (int j = 0; j < 8; ++j) { uint32_t t = v[j]; cum[base + j] = excl; excl += t; }
        if (threadIdx.x == 63) cum[SPAN_MAX] = inc;   // covers blkN == SPAN_MAX
    }
    __syncthreads();

    const int wave = threadIdx.x >> 6, lane = threadIdx.x & 63;
    const uint32_t T = cum[blkN];

    // contiguous flat slice per wave
    const uint32_t chunk = (T + 3) >> 2;
    const uint32_t f0    = (uint32_t)wave * chunk;
    uint32_t fend        = f0 + chunk;
    if (fend > T) fend = T;

    if (f0 < fend) {
        // seed run index: binary search for run containing f0 (wave-uniform)
        int l = 0, r = blkN;
        while (l < r) {
            int m = (l + r) >> 1;
            if (cum[m + 1] <= f0) l = m + 1; else r = m;
        }
        int i = l;

        for (uint32_t fb = f0; fb < fend; fb += 64) {
            uint32_t f = fb + lane;
            int ii = i;
            if (f < fend) {
                // monotonic advance (empty runs skipped)
                while (cum[ii + 1] <= f) ++ii;
                uint32_t k = f - cum[ii];
                size_t addr = (size_t)(blk0 + ii) * EPB + offLo[ii] + k;
                uint32_t sl = sl_in[addr];
                float rr = __half2float(__ushort_as_half(r_in[addr]));
                float ss = sigma[sl >> WSHIFT];
                float sd = sig[sl & (WINDOW - 1)];
                float v  = edge_val(rr, fmaf(ss, ss, sd * sd));
                atomicAdd(&acc[sl & (WINDOW - 1)], v);
            }
            i = __shfl(ii, 63);   // lane 63 holds the furthest run
        }
    }
    __syncthreads();

    // coalesced nt float4 flush
    vfloat4* outp = (vfloat4*)(partials + (size_t)g * WINDOW);
    for (int i = threadIdx.x; i < WINDOW / 4; i += 256)
        __builtin_nontemporal_store(accv[i], outp + i);
}

// ---------------- pass 3: reduce partials, apply charge ----------------
template<int WPB>
__global__ __launch_bounds__(256) void p3_reduce(
    const float* __restrict__ partials,
    const float* __restrict__ charge,
    float*       __restrict__ out, int n_nodes)
{
    int n = blockIdx.x * 256 + threadIdx.x;
    if (n >= n_nodes) return;
    unsigned b     = (unsigned)n >> WSHIFT;
    unsigned local = (unsigned)n & (WINDOW - 1);
    const float* p = partials + ((size_t)b * WPB) * WINDOW + local;
    float sum = 0.0f;
    #pragma unroll
    for (int w = 0; w < WPB; ++w)
        sum += __builtin_nontemporal_load(p + (size_t)w * WINDOW);
    out[n] = charge[n] * sum;
}

// ---------------- fallback: direct far-atomic ----------------
__global__ __launch_bounds__(256) void edge_msg_atomic(
    const float* __restrict__ charge, const float* __restrict__ sigma,
    const float* __restrict__ bond, const int* __restrict__ src,
    const int* __restrict__ dst, float* __restrict__ out, int n_edges)
{
    int i = blockIdx.x * blockDim.x + threadIdx.x;
    if (i < n_edges) {
        float ss = sigma[src[i]], sd = sigma[dst[i]];
        float msg = charge[dst[i]] * edge_val(bond[i], fmaf(ss, ss, sd * sd));
        atomicAdd(&out[dst[i]], msg);
    }
}

extern "C" void kernel_launch(void* const* d_in, const int* in_sizes, int n_in,
                              void* d_out, int out_size, void* d_ws, size_t ws_size,
                              hipStream_t stream) {
    const float* charge = (const float*)d_in[0];
    const float* sigma  = (const float*)d_in[1];
    const float* bond   = (const float*)d_in[2];
    const int*   src    = (const int*)d_in[3];
    const int*   dst    = (const int*)d_in[4];
    float* out = (float*)d_out;

    int n_nodes = in_sizes[0];
    int n_edges = in_sizes[2];

    int nblk = (n_edges + EPB - 1) / EPB;

    // ws: offs [nblk][256] u16 | sl [nblk][EPB] u32 | r [nblk][EPB] u16 | partials
    size_t offs_b = (size_t)nblk * OFFS_STRIDE * sizeof(unsigned short);
    size_t sl_b   = (size_t)nblk * EPB * sizeof(uint32_t);
    size_t r_b    = (size_t)nblk * EPB * sizeof(unsigned short);
    size_t base_b = offs_b + sl_b + r_b;

    // pick widest WPB whose partials fit the workspace & span fits LDS table
    int wpb = 0;
    {
        size_t p16 = (size_t)NB * 16 * WINDOW * sizeof(float);
        size_t p8  = (size_t)NB * 8  * WINDOW * sizeof(float);
        int span16 = (nblk + 15) / 16, span8 = (nblk + 7) / 8;
        if (base_b + p16 <= ws_size && span16 <= SPAN_MAX) wpb = 16;
        else if (base_b + p8 <= ws_size && span8 <= SPAN_MAX) wpb = 8;
    }

    if (n_nodes <= NB * WINDOW && wpb != 0) {
        unsigned short* offs = (unsigned short*)d_ws;
        uint32_t*       slp  = (uint32_t*)((char*)d_ws + offs_b);
        unsigned short* rp   = (unsigned short*)((char*)d_ws + offs_b + sl_b);
        float* partial = (float*)((char*)d_ws + base_b);

        p1_bin<<<nblk, 256, 0, stream>>>(bond, src, dst, offs, slp, rp, n_edges);
        int blocks3 = (n_nodes + 255) / 256;
        if (wpb == 16) {
            p2_acc<16><<<NB * 16, 256, 0, stream>>>(slp, rp, offs, sigma, partial,
                                                    n_nodes, nblk);
            p3_reduce<16><<<blocks3, 256, 0, stream>>>(partial, charge, out, n_nodes);
        } else {
            p2_acc<8><<<NB * 8, 256, 0, stream>>>(slp, rp, offs, sigma, partial,
                                                  n_nodes, nblk);
            p3_reduce<8><<<blocks3, 256, 0, stream>>>(partial, charge, out, n_nodes);
        }
    } else {
        // fallback: direct atomics (correct, slower)
        (void)hipMemsetAsync(out, 0, (size_t)n_nodes * sizeof(float), stream);
        int blocks = (n_edges + 255) / 256;
        edge_msg_atomic<<<blocks, 256, 0, stream>>>(charge, sigma, bond, src, dst,
                                                    out, n_edges);
    }
}

// Round 7
// 327.638 us; speedup vs baseline: 1.2534x; 1.0049x over previous
//
#include <hip/hip_runtime.h>
#include <hip/hip_fp16.h>
#include <math.h>
#include <stdint.h>

// ---------------- problem constants ----------------
#define CUTOFF_F     5.0f
#define INV_CUTOFF   0.2f
#define KCOUL        14.3996454784936f
#define INV_SQRT2    0.7071067811865475f

// clang native vectors (HIP_vector_type is rejected by nontemporal builtins)
typedef int            vint4    __attribute__((ext_vector_type(4)));
typedef float          vfloat4  __attribute__((ext_vector_type(4)));
typedef uint32_t       vuint4   __attribute__((ext_vector_type(4)));
typedef unsigned short vushort8 __attribute__((ext_vector_type(8)));

// ---------------- plan ----------------
// ROUND-7: FIX p1'S REGISTER SPILLS (p1 ~170us is now the top dispatch;
// HBM roofline for its 288MB is ~46us). Old p1 loaded 12 vec4 (48 VGPR)
// up-front + unpack arrays + 6 packed arrays across the scan barrier:
// peak live ~90 vs 44 allocated => scratch spill/fill every block (low
// VALUBusy 5.6%, r5 WRITE_SIZE 76MB over payload). Restructure: per batch
// {load 6 vec4 -> pack+hist immediately -> vec regs die}; launch_bounds
// (256,4) so RA keeps ~65-70 live regs without spilling. LDS 26.5KB ->
// 6 WG/CU.
// p2/p3: byte-identical to round 6 (best measured: p2 142us @79% occ).
#define WSHIFT        11
#define WINDOW        2048
#define NB            245                       // ceil(500000/2048)
#define EPT           8
#define EPB           4096                      // 2 batches * 256 thr * 8
#define OFFS_STRIDE   256                       // u16 slots per block (246 used)
#define SPAN_MAX      512                       // max p1-blocks per p2 wg

// A&S 7.1.26 erf approx, x>=0, max abs err 1.5e-7
__device__ __forceinline__ float erf_approx(float x) {
    const float a1 = 0.254829592f, a2 = -0.284496736f, a3 = 1.421413741f,
                a4 = -1.453152027f, a5 = 1.061405429f, p = 0.3275911f;
    float t = __builtin_amdgcn_rcpf(fmaf(p, x, 1.0f));
    float poly = t * fmaf(t, fmaf(t, fmaf(t, fmaf(t, a5, a4), a3), a2), a1);
    return 1.0f - poly * __expf(-x * x);
}

// per-edge value WITHOUT the charge[dst] factor; s2sum = sig_s^2 + sig_d^2
__device__ __forceinline__ float edge_val(float rr, float s2sum) {
    float inv_gamma = rsqrtf(s2sum);
    float x  = rr * INV_CUTOFF;
    float fc = fmaf(x * x * x, fmaf(x, fmaf(-6.0f, x, 15.0f), -10.0f), 1.0f);
    fc = (rr <= CUTOFF_F) ? fc : 0.0f;
    return erf_approx(rr * INV_SQRT2 * inv_gamma) * fc * KCOUL
         * __builtin_amdgcn_rcpf(rr);
}

// ---------------- pass 1: block-major streaming counting-sort ----------------
// Spill-free restructure: batch A {load->pack} then batch B {load->pack}.
__global__ __launch_bounds__(256, 4) void p1_bin(
    const float* __restrict__ bond,
    const int*   __restrict__ src,
    const int*   __restrict__ dst,
    unsigned short* __restrict__ offs,    // [nblk][OFFS_STRIDE] u16 scan table
    uint32_t*       __restrict__ sl_out,  // [nblk][EPB] (src<<11 | local_dst)
    unsigned short* __restrict__ r_out,   // [nblk][EPB] fp16 bond length
    int n_edges)
{
    __shared__ uint32_t hist[NB];
    __shared__ uint32_t scan_s[NB + 1];
    __shared__ alignas(16) uint32_t       buf_sl[EPB];   // 16 KB
    __shared__ alignas(16) unsigned short buf_r[EPB];    //  8 KB

    const int tid = threadIdx.x;
    const int e0  = blockIdx.x * EPB;

    if (tid < NB) hist[tid] = 0;
    __syncthreads();

    uint32_t slA[EPT], brA[EPT], slB[EPT], brB[EPT];
    unsigned short hrA[EPT], hrB[EPT];

    const bool full = (e0 + EPB <= n_edges);
    if (full) {
        // ---- batch A: 6 vec4 loads, pack immediately, vec regs die ----
        {
            const vint4*   dp = (const vint4*)(dst + e0) + tid;
            const vint4*   sp = (const vint4*)(src + e0) + tid;
            const vfloat4* rp = (const vfloat4*)(bond + e0) + tid;
            vint4   d0 = __builtin_nontemporal_load(dp);
            vint4   d1 = __builtin_nontemporal_load(dp + 256);
            vint4   s0 = __builtin_nontemporal_load(sp);
            vint4   s1 = __builtin_nontemporal_load(sp + 256);
            vfloat4 r0 = __builtin_nontemporal_load(rp);
            vfloat4 r1 = __builtin_nontemporal_load(rp + 256);
            int   d[EPT] = {d0.x,d0.y,d0.z,d0.w,d1.x,d1.y,d1.z,d1.w};
            int   s[EPT] = {s0.x,s0.y,s0.z,s0.w,s1.x,s1.y,s1.z,s1.w};
            float r[EPT] = {r0.x,r0.y,r0.z,r0.w,r1.x,r1.y,r1.z,r1.w};
            #pragma unroll
            for (int j = 0; j < EPT; ++j) {
                unsigned b = (unsigned)d[j] >> WSHIFT;
                uint32_t rk = atomicAdd(&hist[b], 1u);
                brA[j] = (b << 16) | rk;
                slA[j] = ((uint32_t)s[j] << WSHIFT) | ((unsigned)d[j] & (WINDOW - 1));
                hrA[j] = __half_as_ushort(__float2half_rn(r[j]));
            }
        }
        // ---- batch B: same, offsets +512/+768 ----
        {
            const vint4*   dp = (const vint4*)(dst + e0) + tid;
            const vint4*   sp = (const vint4*)(src + e0) + tid;
            const vfloat4* rp = (const vfloat4*)(bond + e0) + tid;
            vint4   d2 = __builtin_nontemporal_load(dp + 512);
            vint4   d3 = __builtin_nontemporal_load(dp + 768);
            vint4   s2 = __builtin_nontemporal_load(sp + 512);
            vint4   s3 = __builtin_nontemporal_load(sp + 768);
            vfloat4 r2 = __builtin_nontemporal_load(rp + 512);
            vfloat4 r3 = __builtin_nontemporal_load(rp + 768);
            int   d[EPT] = {d2.x,d2.y,d2.z,d2.w,d3.x,d3.y,d3.z,d3.w};
            int   s[EPT] = {s2.x,s2.y,s2.z,s2.w,s3.x,s3.y,s3.z,s3.w};
            float r[EPT] = {r2.x,r2.y,r2.z,r2.w,r3.x,r3.y,r3.z,r3.w};
            #pragma unroll
            for (int j = 0; j < EPT; ++j) {
                unsigned b = (unsigned)d[j] >> WSHIFT;
                uint32_t rk = atomicAdd(&hist[b], 1u);
                brB[j] = (b << 16) | rk;
                slB[j] = ((uint32_t)s[j] << WSHIFT) | ((unsigned)d[j] & (WINDOW - 1));
                hrB[j] = __half_as_ushort(__float2half_rn(r[j]));
            }
        }
    } else {
        #pragma unroll
        for (int j = 0; j < EPT; ++j) {
            int eA = e0 + (j >> 2) * 1024 + tid * 4 + (j & 3);
            int eB = eA + 2048;
            if (eA < n_edges) {
                int dv = dst[eA]; int sv = src[eA]; float rv = bond[eA];
                unsigned b = (unsigned)dv >> WSHIFT;
                uint32_t rk = atomicAdd(&hist[b], 1u);
                brA[j] = (b << 16) | rk;
                slA[j] = ((uint32_t)sv << WSHIFT) | ((unsigned)dv & (WINDOW - 1));
                hrA[j] = __half_as_ushort(__float2half_rn(rv));
            } else brA[j] = 0xFFFFFFFFu;
            if (eB < n_edges) {
                int dv = dst[eB]; int sv = src[eB]; float rv = bond[eB];
                unsigned b = (unsigned)dv >> WSHIFT;
                uint32_t rk = atomicAdd(&hist[b], 1u);
                brB[j] = (b << 16) | rk;
                slB[j] = ((uint32_t)sv << WSHIFT) | ((unsigned)dv & (WINDOW - 1));
                hrB[j] = __half_as_ushort(__float2half_rn(rv));
            } else brB[j] = 0xFFFFFFFFu;
        }
    }
    __syncthreads();

    // wave scan over NB buckets, 4 elems/lane (first wave, 256 >= NB+1)
    if (tid < 64) {
        const int base = tid * 4;
        uint32_t v[4]; uint32_t s = 0;
        #pragma unroll
        for (int j = 0; j < 4; ++j) { v[j] = (base + j < NB) ? hist[base + j] : 0u; s += v[j]; }
        uint32_t inc = s;
        #pragma unroll
        for (int d = 1; d < 64; d <<= 1) {
            uint32_t up = __shfl_up(inc, d, 64);
            if (tid >= d) inc += up;
        }
        uint32_t excl = inc - s;
        #pragma unroll
        for (int j = 0; j < 4; ++j) {
            if (base + j <= NB) scan_s[base + j] = excl;
            excl += v[j];
        }
    }
    __syncthreads();

    // register -> LDS scatter at scan[b] + rank
    #pragma unroll
    for (int j = 0; j < EPT; ++j)
        if (brA[j] != 0xFFFFFFFFu) {
            uint32_t p = scan_s[brA[j] >> 16] + (brA[j] & 0xFFFFu);
            buf_sl[p] = slA[j]; buf_r[p] = hrA[j];
        }
    #pragma unroll
    for (int j = 0; j < EPT; ++j)
        if (brB[j] != 0xFFFFFFFFu) {
            uint32_t p = scan_s[brB[j] >> 16] + (brB[j] & 0xFFFFu);
            buf_sl[p] = slB[j]; buf_r[p] = hrB[j];
        }
    __syncthreads();

    // offset table: the LDS scan, dumped as u16 (246 entries)
    if (tid <= NB)
        offs[(size_t)blockIdx.x * OFFS_STRIDE + tid] = (unsigned short)scan_s[tid];

    // dense block-major dump: fully coalesced vector stores, no checks
    {
        const vuint4* bs = (const vuint4*)buf_sl;
        vuint4* os = (vuint4*)(sl_out + (size_t)blockIdx.x * EPB);
        #pragma unroll
        for (int i = 0; i < EPB / 4 / 256; ++i)      // 4 iterations
            __builtin_nontemporal_store(bs[tid + i * 256], os + tid + i * 256);
        const vushort8* br = (const vushort8*)buf_r;
        vushort8* orr = (vushort8*)(r_out + (size_t)blockIdx.x * EPB);
        #pragma unroll
        for (int i = 0; i < EPB / 8 / 256; ++i)      // 2 iterations
            __builtin_nontemporal_store(br[tid + i * 256], orr + tid + i * 256);
    }
}

// ---------------- pass 2: flat dense walk + LDS-window accumulate ----------------
// UNCHANGED from round 6 (best measured: 142us @79% occ).
template<int WPB>
__global__ __launch_bounds__(256, 4) void p2_acc(
    const uint32_t*       __restrict__ sl_in,
    const unsigned short* __restrict__ r_in,
    const unsigned short* __restrict__ offs,
    const float*          __restrict__ sigma,
    float*                __restrict__ partials,  // [NB*WPB][WINDOW]
    int n_nodes, int nblk)
{
    __shared__ float acc[WINDOW];                  // 8 KB
    __shared__ float sig[WINDOW];                  // 8 KB — dst-side sigma
    __shared__ unsigned short offLo[SPAN_MAX];     // 1 KB
    __shared__ uint32_t cum[SPAN_MAX + 1];         // 2 KB — flat prefix of run lens

    const int g = blockIdx.x;
    const int b = g / WPB;
    const int w = g % WPB;

    vfloat4* accv = (vfloat4*)acc;
    for (int i = threadIdx.x; i < WINDOW / 4; i += 256)
        accv[i] = (vfloat4){0.f, 0.f, 0.f, 0.f};

    const int nbase  = b << WSHIFT;
    const int nvalid = (n_nodes - nbase < WINDOW) ? (n_nodes - nbase) : WINDOW;
    if (nvalid == WINDOW) {
        vfloat4* sv = (vfloat4*)sig;
        const vfloat4* gp = (const vfloat4*)(sigma + nbase);
        for (int i = threadIdx.x; i < WINDOW / 4; i += 256) sv[i] = gp[i];
    } else {
        for (int i = threadIdx.x; i < WINDOW; i += 256)
            sig[i] = (i < nvalid) ? sigma[nbase + i] : 0.f;
    }

    // my span of p1 blocks; stage offLo + run lengths (len into cum[] temp)
    const int span = (nblk + WPB - 1) / WPB;
    const int blk0 = w * span;
    int blkN = nblk - blk0;
    if (blkN > span) blkN = span;
    if (blkN < 0) blkN = 0;
    for (int i = threadIdx.x; i < blkN; i += 256) {
        size_t o = (size_t)(blk0 + i) * OFFS_STRIDE + b;
        unsigned short lo = offs[o];
        offLo[i] = lo;
        cum[i] = (uint32_t)offs[o + 1] - lo;     // run length (temp)
    }
    __syncthreads();

    // wave-0 exclusive scan of run lengths, 8 elems/lane (SPAN_MAX=512=64*8).
    // Positions >= blkN scan zeros, so cum[blkN] = total automatically.
    if (threadIdx.x < 64) {
        const int base = threadIdx.x * 8;
        uint32_t v[8]; uint32_t s = 0;
        #pragma unroll
        for (int j = 0; j < 8; ++j) { v[j] = (base + j < blkN) ? cum[base + j] : 0u; s += v[j]; }
        uint32_t inc = s;
        #pragma unroll
        for (int d = 1; d < 64; d <<= 1) {
            uint32_t up = __shfl_up(inc, d, 64);
            if (threadIdx.x >= d) inc += up;
        }
        uint32_t excl = inc - s;
        #pragma unroll
        for (int j = 0; j < 8; ++j) { uint32_t t = v[j]; cum[base + j] = excl; excl += t; }
        if (threadIdx.x == 63) cum[SPAN_MAX] = inc;   // covers blkN == SPAN_MAX
    }
    __syncthreads();

    const int wave = threadIdx.x >> 6, lane = threadIdx.x & 63;
    const uint32_t T = cum[blkN];

    // contiguous flat slice per wave
    const uint32_t chunk = (T + 3) >> 2;
    const uint32_t f0    = (uint32_t)wave * chunk;
    uint32_t fend        = f0 + chunk;
    if (fend > T) fend = T;

    if (f0 < fend) {
        // seed run index: binary search for run containing f0 (wave-uniform)
        int l = 0, r = blkN;
        while (l < r) {
            int m = (l + r) >> 1;
            if (cum[m + 1] <= f0) l = m + 1; else r = m;
        }
        int i = l;

        for (uint32_t fb = f0; fb < fend; fb += 64) {
            uint32_t f = fb + lane;
            int ii = i;
            if (f < fend) {
                // monotonic advance (empty runs skipped)
                while (cum[ii + 1] <= f) ++ii;
                uint32_t k = f - cum[ii];
                size_t addr = (size_t)(blk0 + ii) * EPB + offLo[ii] + k;
                uint32_t sl = sl_in[addr];
                float rr = __half2float(__ushort_as_half(r_in[addr]));
                float ss = sigma[sl >> WSHIFT];
                float sd = sig[sl & (WINDOW - 1)];
                float v  = edge_val(rr, fmaf(ss, ss, sd * sd));
                atomicAdd(&acc[sl & (WINDOW - 1)], v);
            }
            i = __shfl(ii, 63);   // lane 63 holds the furthest run
        }
    }
    __syncthreads();

    // coalesced nt float4 flush
    vfloat4* outp = (vfloat4*)(partials + (size_t)g * WINDOW);
    for (int i = threadIdx.x; i < WINDOW / 4; i += 256)
        __builtin_nontemporal_store(accv[i], outp + i);
}

// ---------------- pass 3: reduce partials, apply charge ----------------
template<int WPB>
__global__ __launch_bounds__(256) void p3_reduce(
    const float* __restrict__ partials,
    const float* __restrict__ charge,
    float*       __restrict__ out, int n_nodes)
{
    int n = blockIdx.x * 256 + threadIdx.x;
    if (n >= n_nodes) return;
    unsigned b     = (unsigned)n >> WSHIFT;
    unsigned local = (unsigned)n & (WINDOW - 1);
    const float* p = partials + ((size_t)b * WPB) * WINDOW + local;
    float sum = 0.0f;
    #pragma unroll
    for (int w = 0; w < WPB; ++w)
        sum += __builtin_nontemporal_load(p + (size_t)w * WINDOW);
    out[n] = charge[n] * sum;
}

// ---------------- fallback: direct far-atomic ----------------
__global__ __launch_bounds__(256) void edge_msg_atomic(
    const float* __restrict__ charge, const float* __restrict__ sigma,
    const float* __restrict__ bond, const int* __restrict__ src,
    const int* __restrict__ dst, float* __restrict__ out, int n_edges)
{
    int i = blockIdx.x * blockDim.x + threadIdx.x;
    if (i < n_edges) {
        float ss = sigma[src[i]], sd = sigma[dst[i]];
        float msg = charge[dst[i]] * edge_val(bond[i], fmaf(ss, ss, sd * sd));
        atomicAdd(&out[dst[i]], msg);
    }
}

extern "C" void kernel_launch(void* const* d_in, const int* in_sizes, int n_in,
                              void* d_out, int out_size, void* d_ws, size_t ws_size,
                              hipStream_t stream) {
    const float* charge = (const float*)d_in[0];
    const float* sigma  = (const float*)d_in[1];
    const float* bond   = (const float*)d_in[2];
    const int*   src    = (const int*)d_in[3];
    const int*   dst    = (const int*)d_in[4];
    float* out = (float*)d_out;

    int n_nodes = in_sizes[0];
    int n_edges = in_sizes[2];

    int nblk = (n_edges + EPB - 1) / EPB;

    // ws: offs [nblk][256] u16 | sl [nblk][EPB] u32 | r [nblk][EPB] u16 | partials
    size_t offs_b = (size_t)nblk * OFFS_STRIDE * sizeof(unsigned short);
    size_t sl_b   = (size_t)nblk * EPB * sizeof(uint32_t);
    size_t r_b    = (size_t)nblk * EPB * sizeof(unsigned short);
    size_t base_b = offs_b + sl_b + r_b;

    // pick widest WPB whose partials fit the workspace & span fits LDS table
    int wpb = 0;
    {
        size_t p16 = (size_t)NB * 16 * WINDOW * sizeof(float);
        size_t p8  = (size_t)NB * 8  * WINDOW * sizeof(float);
        int span16 = (nblk + 15) / 16, span8 = (nblk + 7) / 8;
        if (base_b + p16 <= ws_size && span16 <= SPAN_MAX) wpb = 16;
        else if (base_b + p8 <= ws_size && span8 <= SPAN_MAX) wpb = 8;
    }

    if (n_nodes <= NB * WINDOW && wpb != 0) {
        unsigned short* offs = (unsigned short*)d_ws;
        uint32_t*       slp  = (uint32_t*)((char*)d_ws + offs_b);
        unsigned short* rp   = (unsigned short*)((char*)d_ws + offs_b + sl_b);
        float* partial = (float*)((char*)d_ws + base_b);

        p1_bin<<<nblk, 256, 0, stream>>>(bond, src, dst, offs, slp, rp, n_edges);
        int blocks3 = (n_nodes + 255) / 256;
        if (wpb == 16) {
            p2_acc<16><<<NB * 16, 256, 0, stream>>>(slp, rp, offs, sigma, partial,
                                                    n_nodes, nblk);
            p3_reduce<16><<<blocks3, 256, 0, stream>>>(partial, charge, out, n_nodes);
        } else {
            p2_acc<8><<<NB * 8, 256, 0, stream>>>(slp, rp, offs, sigma, partial,
                                                  n_nodes, nblk);
            p3_reduce<8><<<blocks3, 256, 0, stream>>>(partial, charge, out, n_nodes);
        }
    } else {
        // fallback: direct atomics (correct, slower)
        (void)hipMemsetAsync(out, 0, (size_t)n_nodes * sizeof(float), stream);
        int blocks = (n_edges + 255) / 256;
        edge_msg_atomic<<<blocks, 256, 0, stream>>>(charge, sigma, bond, src, dst,
                                                    out, n_edges);
    }
}